// Round 1
// baseline (47426.614 us; speedup 1.0000x reference)
//
#include <hip/hip_runtime.h>
#include <stdint.h>
#include <math.h>

// Problem constants
#define TT   512      // sequence length / decode steps
#define HH_  1024     // hidden (encoder concat / decoder)
#define H2_  512      // encoder per-direction hidden
#define VV   32000    // vocab
#define NB   256      // persistent blocks (1 per CU -> guaranteed co-resident)
#define BT   512      // threads per block (8 waves)

// ws layout (float offsets)
#define OF_XS0 16
#define OF_XS1 (OF_XS0 + TT*HH_)
#define OF_EH  (OF_XS1 + TT*HH_)        // enc h ping-pong [2 par][2 dir][512]
#define OF_EC  (OF_EH + 2048)           // enc c [2 dir][512]
#define OF_HHF (OF_EC + 1024)           // enc final h [2 layer][1024]
#define OF_CCF (OF_HHF + 2048)          // enc final c
#define OF_DH  (OF_CCF + 2048)          // dec h [2 layer][2 par][1024]
#define OF_DC  (OF_DH + 4096)           // dec c [2 layer][1024]
#define OF_LOG (OF_DC + 2048)           // logits [512][32000]

struct Ctl { int cnt; int gen; int pad[2]; unsigned long long slot[2]; };

__device__ __forceinline__ float wredsum(float v){
#pragma unroll
  for (int s = 32; s > 0; s >>= 1) v += __shfl_xor(v, s, 64);
  return v;
}
__device__ __forceinline__ float sigm(float x){ return 1.f/(1.f + __expf(-x)); }
__device__ __forceinline__ float tanh_(float x){
  float e = __expf(-2.f*fabsf(x));      // in (0,1], no overflow
  float t = (1.f - e)/(1.f + e);
  return copysignf(t, x);
}
// order-preserving float pack + first-index tie-break (matches jnp.argmax)
__device__ __forceinline__ unsigned long long packmax(float v, int idx){
  unsigned u = __float_as_uint(v);
  u = (u & 0x80000000u) ? ~u : (u | 0x80000000u);
  return ((unsigned long long)u << 32) | (unsigned)(~idx);
}

// device-scope grid barrier (generation-based; 256 arrivals)
__device__ __forceinline__ void gridbar(Ctl* c){
  __syncthreads();
  if (threadIdx.x == 0) {
    __builtin_amdgcn_fence(__ATOMIC_RELEASE, "agent");
    int g = __hip_atomic_load(&c->gen, __ATOMIC_RELAXED, __HIP_MEMORY_SCOPE_AGENT);
    int v = __hip_atomic_fetch_add(&c->cnt, 1, __ATOMIC_RELAXED, __HIP_MEMORY_SCOPE_AGENT);
    if (v == NB-1) {
      __hip_atomic_store(&c->cnt, 0, __ATOMIC_RELAXED, __HIP_MEMORY_SCOPE_AGENT);
      __hip_atomic_store(&c->gen, g+1, __ATOMIC_RELEASE, __HIP_MEMORY_SCOPE_AGENT);
    } else {
      while (__hip_atomic_load(&c->gen, __ATOMIC_RELAXED, __HIP_MEMORY_SCOPE_AGENT) == g)
        __builtin_amdgcn_s_sleep(1);
    }
    __builtin_amdgcn_fence(__ATOMIC_ACQUIRE, "agent");
  }
  __syncthreads();
}

__global__ __launch_bounds__(BT, 1) void seq2seq_k(
    const int*   __restrict__ x,
    const float* __restrict__ enc_emb,
    const float* __restrict__ enc_Wih,   // [2][2][2048][1024]
    const float* __restrict__ enc_Whh,   // [2][2][2048][512]
    const float* __restrict__ enc_b,     // [2][2][2048]
    const float* __restrict__ dec_emb,
    const float* __restrict__ dec_Wih,   // [2][4096][1024]
    const float* __restrict__ dec_Whh,   // [2][4096][1024]
    const float* __restrict__ dec_b,     // [2][4096]
    const float* __restrict__ clf_W,     // [32000][1024]
    const float* __restrict__ clf_b,     // [32000]
    float* __restrict__ ws)
{
  Ctl* ctl = (Ctl*)ws;
  const int blk = blockIdx.x, tid = threadIdx.x;
  const int wave = tid >> 6, lane = tid & 63;
  float* xs0 = ws + OF_XS0;
  float* xs1 = ws + OF_XS1;
  float* EH  = ws + OF_EH;
  float* EC  = ws + OF_EC;
  float* HHf = ws + OF_HHF;
  float* CCf = ws + OF_CCF;
  float* DH  = ws + OF_DH;
  float* DC  = ws + OF_DC;
  float* LG  = ws + OF_LOG;

  __shared__ float sg[4][2][4];   // [pair][khalf][gate]
  __shared__ float cbv[8];
  __shared__ int   cbi[8];

  // ---- P0: embed encoder input, zero encoder states ----
  for (int i = blk*BT + tid; i < TT*HH_; i += NB*BT) {
    int t = i >> 10, d = i & 1023;
    xs0[i] = enc_emb[(size_t)x[t]*HH_ + d];
  }
  for (int i = blk*BT + tid; i < 3072; i += NB*BT) EH[i] = 0.f; // EH(2048)+EC(1024) contiguous
  gridbar(ctl);

  // ---- encoder: 2 layers, fwd+bwd concurrent, 1 barrier per step ----
  const float* xsrc = xs0;
#pragma unroll 1
  for (int l = 0; l < 2; ++l) {
    const float* Wih = enc_Wih + (size_t)l*2*2048*1024;
    const float* Whh = enc_Whh + (size_t)l*2*2048*512;
    const float* Bb  = enc_b  + l*2*2048;
#pragma unroll 1
    for (int s = 0; s < TT; ++s) {
      const int par = s & 1;
      {
        const int pl = wave >> 1, half = wave & 1;   // 2 waves per (dir,j)
        const int p = blk*4 + pl;                    // 1024 pairs total
        const int dir = p >> 9, j = p & 511;
        const int t = dir ? (TT-1-s) : s;
        const float* xr = xsrc + (size_t)t*HH_;
        const float* hS = EH + par*1024 + dir*512;
        const float* wb = Wih + (size_t)dir*2048*1024;
        const float* hb = Whh + (size_t)dir*2048*512;
        float a0=0,a1=0,a2=0,a3=0;
#pragma unroll
        for (int it = 0; it < 8; ++it) {
          int k = it*128 + half*64 + lane;
          float xv = xr[k];
          a0 += wb[(size_t)(0*512+j)*1024 + k]*xv;
          a1 += wb[(size_t)(1*512+j)*1024 + k]*xv;
          a2 += wb[(size_t)(2*512+j)*1024 + k]*xv;
          a3 += wb[(size_t)(3*512+j)*1024 + k]*xv;
        }
#pragma unroll
        for (int it = 0; it < 4; ++it) {
          int k = it*128 + half*64 + lane;
          float hv = hS[k];
          a0 += hb[(size_t)(0*512+j)*512 + k]*hv;
          a1 += hb[(size_t)(1*512+j)*512 + k]*hv;
          a2 += hb[(size_t)(2*512+j)*512 + k]*hv;
          a3 += hb[(size_t)(3*512+j)*512 + k]*hv;
        }
        a0 = wredsum(a0); a1 = wredsum(a1); a2 = wredsum(a2); a3 = wredsum(a3);
        if (lane == 0) { sg[pl][half][0]=a0; sg[pl][half][1]=a1; sg[pl][half][2]=a2; sg[pl][half][3]=a3; }
      }
      __syncthreads();
      if (tid < 4) {
        const int p = blk*4 + tid;
        const int dir = p >> 9, j = p & 511;
        const int t = dir ? (TT-1-s) : s;
        float gi = sg[tid][0][0]+sg[tid][1][0] + Bb[dir*2048 + 0*512 + j];
        float gf = sg[tid][0][1]+sg[tid][1][1] + Bb[dir*2048 + 1*512 + j];
        float gg = sg[tid][0][2]+sg[tid][1][2] + Bb[dir*2048 + 2*512 + j];
        float go = sg[tid][0][3]+sg[tid][1][3] + Bb[dir*2048 + 3*512 + j];
        float c  = EC[dir*512 + j];
        float cn = sigm(gf)*c + sigm(gi)*tanh_(gg);
        float hn = sigm(go)*tanh_(cn);
        EC[dir*512 + j] = cn;
        EH[(par^1)*1024 + dir*512 + j] = hn;
        if (l == 0) xs1[(size_t)t*HH_ + dir*512 + j] = hn;
        if (s == TT-1) { HHf[l*1024 + dir*512 + j] = hn; CCf[l*1024 + dir*512 + j] = cn; }
      }
      gridbar(ctl);
    }
    if (l == 0) {
      for (int i = blk*BT + tid; i < 3072; i += NB*BT) EH[i] = 0.f;
      xsrc = xs1;
      gridbar(ctl);
    }
  }

  // ---- decoder init: h/c <- encoder finals, zero argmax slots ----
  for (int i = blk*BT + tid; i < 2048; i += NB*BT) {
    int l = i >> 10, d = i & 1023;
    DH[(l*2 + 0)*1024 + d] = HHf[i];
    DH[(l*2 + 1)*1024 + d] = 0.f;
    DC[i] = CCf[i];
  }
  if (blk == 0 && tid == 0) { ctl->slot[0] = 0ull; ctl->slot[1] = 0ull; }
  gridbar(ctl);

  // ---- decoder: 512 steps x {L1 cell | L2 cell | clf+argmax} ----
#pragma unroll 1
  for (int t = 0; t < TT; ++t) {
    const int par = t & 1;
    int tok;
    if (t == 0) tok = 1;  // START_IDX
    else {
      unsigned long long pk = __hip_atomic_load(&ctl->slot[(t-1)&1], __ATOMIC_RELAXED, __HIP_MEMORY_SCOPE_AGENT);
      tok = (int)(~(unsigned)(pk & 0xFFFFFFFFull));
    }
    const float* xt = dec_emb + (size_t)tok*HH_;

    // phase A: layer 0 cell
    {
      const float* Wih = dec_Wih;
      const float* Whh = dec_Whh;
      const float* hS  = DH + (0*2 + par)*1024;
      const int pl = wave >> 1, half = wave & 1;
      const int j = blk*4 + pl;
      float a0=0,a1=0,a2=0,a3=0;
#pragma unroll
      for (int it = 0; it < 8; ++it) {
        int k = it*128 + half*64 + lane;
        float xv = xt[k];
        a0 += Wih[(size_t)(0*1024+j)*1024 + k]*xv;
        a1 += Wih[(size_t)(1*1024+j)*1024 + k]*xv;
        a2 += Wih[(size_t)(2*1024+j)*1024 + k]*xv;
        a3 += Wih[(size_t)(3*1024+j)*1024 + k]*xv;
      }
#pragma unroll
      for (int it = 0; it < 8; ++it) {
        int k = it*128 + half*64 + lane;
        float hv = hS[k];
        a0 += Whh[(size_t)(0*1024+j)*1024 + k]*hv;
        a1 += Whh[(size_t)(1*1024+j)*1024 + k]*hv;
        a2 += Whh[(size_t)(2*1024+j)*1024 + k]*hv;
        a3 += Whh[(size_t)(3*1024+j)*1024 + k]*hv;
      }
      a0 = wredsum(a0); a1 = wredsum(a1); a2 = wredsum(a2); a3 = wredsum(a3);
      if (lane == 0) { sg[pl][half][0]=a0; sg[pl][half][1]=a1; sg[pl][half][2]=a2; sg[pl][half][3]=a3; }
      __syncthreads();
      if (tid < 4) {
        const int j2 = blk*4 + tid;
        float gi = sg[tid][0][0]+sg[tid][1][0] + dec_b[0*1024 + j2];
        float gf = sg[tid][0][1]+sg[tid][1][1] + dec_b[1*1024 + j2];
        float gg = sg[tid][0][2]+sg[tid][1][2] + dec_b[2*1024 + j2];
        float go = sg[tid][0][3]+sg[tid][1][3] + dec_b[3*1024 + j2];
        float c  = DC[j2];
        float cn = sigm(gf)*c + sigm(gi)*tanh_(gg);
        float hn = sigm(go)*tanh_(cn);
        DC[j2] = cn;
        DH[(0*2 + (par^1))*1024 + j2] = hn;
      }
    }
    gridbar(ctl);

    // phase B: layer 1 cell (input = new h1)
    {
      const float* Wih = dec_Wih + (size_t)4096*1024;
      const float* Whh = dec_Whh + (size_t)4096*1024;
      const float* x2  = DH + (0*2 + (par^1))*1024;
      const float* hS  = DH + (1*2 + par)*1024;
      const int pl = wave >> 1, half = wave & 1;
      const int j = blk*4 + pl;
      float a0=0,a1=0,a2=0,a3=0;
#pragma unroll
      for (int it = 0; it < 8; ++it) {
        int k = it*128 + half*64 + lane;
        float xv = x2[k];
        a0 += Wih[(size_t)(0*1024+j)*1024 + k]*xv;
        a1 += Wih[(size_t)(1*1024+j)*1024 + k]*xv;
        a2 += Wih[(size_t)(2*1024+j)*1024 + k]*xv;
        a3 += Wih[(size_t)(3*1024+j)*1024 + k]*xv;
      }
#pragma unroll
      for (int it = 0; it < 8; ++it) {
        int k = it*128 + half*64 + lane;
        float hv = hS[k];
        a0 += Whh[(size_t)(0*1024+j)*1024 + k]*hv;
        a1 += Whh[(size_t)(1*1024+j)*1024 + k]*hv;
        a2 += Whh[(size_t)(2*1024+j)*1024 + k]*hv;
        a3 += Whh[(size_t)(3*1024+j)*1024 + k]*hv;
      }
      a0 = wredsum(a0); a1 = wredsum(a1); a2 = wredsum(a2); a3 = wredsum(a3);
      if (lane == 0) { sg[pl][half][0]=a0; sg[pl][half][1]=a1; sg[pl][half][2]=a2; sg[pl][half][3]=a3; }
      __syncthreads();
      if (tid < 4) {
        const int j2 = blk*4 + tid;
        float gi = sg[tid][0][0]+sg[tid][1][0] + dec_b[4096 + 0*1024 + j2];
        float gf = sg[tid][0][1]+sg[tid][1][1] + dec_b[4096 + 1*1024 + j2];
        float gg = sg[tid][0][2]+sg[tid][1][2] + dec_b[4096 + 2*1024 + j2];
        float go = sg[tid][0][3]+sg[tid][1][3] + dec_b[4096 + 3*1024 + j2];
        float c  = DC[1024 + j2];
        float cn = sigm(gf)*c + sigm(gi)*tanh_(gg);
        float hn = sigm(go)*tanh_(cn);
        DC[1024 + j2] = cn;
        DH[(1*2 + (par^1))*1024 + j2] = hn;
      }
      if (blk == 0 && tid == 0)   // recycle the slot read at phase A (rewritten at t+2)
        __hip_atomic_store(&ctl->slot[(t+1)&1], 0ull, __ATOMIC_RELAXED, __HIP_MEMORY_SCOPE_AGENT);
    }
    gridbar(ctl);

    // phase C: classifier matvec + logits store + global argmax via atomicMax
    {
      const float* h2 = DH + (1*2 + (par^1))*1024;
      const int gw = blk*8 + wave;            // 2048 waves
      float bv = -INFINITY; int bi = 0;
#pragma unroll 1
      for (int i = 0; i < 16; ++i) {
        int row = gw + i*2048;
        if (row < VV) {
          const float* wr = clf_W + (size_t)row*1024;
          float a = 0.f;
#pragma unroll
          for (int it = 0; it < 16; ++it) { int k = it*64 + lane; a += wr[k]*h2[k]; }
          a = wredsum(a) + clf_b[row];
          if (lane == 0) LG[(size_t)t*VV + row] = a;
          if (a > bv) { bv = a; bi = row; }
        }
      }
      if (lane == 0) { cbv[wave] = bv; cbi[wave] = bi; }
      __syncthreads();
      if (tid == 0) {
        float v = cbv[0]; int ix = cbi[0];
#pragma unroll
        for (int w2 = 1; w2 < 8; ++w2) {
          float v2 = cbv[w2]; int i2 = cbi[w2];
          if (v2 > v || (v2 == v && i2 < ix)) { v = v2; ix = i2; }
        }
        atomicMax(&ctl->slot[t&1], packmax(v, ix));
      }
    }
    gridbar(ctl);
  }
}

// final: softmax rows of LG[T][V], write transposed out[v*T + t]
__global__ __launch_bounds__(256, 1) void softmax_k(const float* __restrict__ LG, float* __restrict__ out){
  const int t = blockIdx.x, tid = threadIdx.x;
  __shared__ float red[256];
  const float* row = LG + (size_t)t*VV;
  float mx = -INFINITY;
  for (int v = tid; v < VV; v += 256) mx = fmaxf(mx, row[v]);
  red[tid] = mx; __syncthreads();
  for (int s = 128; s > 0; s >>= 1) { if (tid < s) red[tid] = fmaxf(red[tid], red[tid+s]); __syncthreads(); }
  mx = red[0]; __syncthreads();
  float sum = 0.f;
  for (int v = tid; v < VV; v += 256) sum += __expf(row[v]-mx);
  red[tid] = sum; __syncthreads();
  for (int s = 128; s > 0; s >>= 1) { if (tid < s) red[tid] += red[tid+s]; __syncthreads(); }
  float inv = 1.f/red[0];
  for (int v = tid; v < VV; v += 256) out[(size_t)v*TT + t] = __expf(row[v]-mx)*inv;
}

extern "C" void kernel_launch(void* const* d_in, const int* in_sizes, int n_in,
                              void* d_out, int out_size, void* d_ws, size_t ws_size,
                              hipStream_t stream) {
  const int*   x       = (const int*)d_in[0];
  const float* enc_emb = (const float*)d_in[1];
  const float* enc_Wih = (const float*)d_in[2];
  const float* enc_Whh = (const float*)d_in[3];
  const float* enc_b   = (const float*)d_in[4];
  const float* dec_emb = (const float*)d_in[5];
  const float* dec_Wih = (const float*)d_in[6];
  const float* dec_Whh = (const float*)d_in[7];
  const float* dec_b   = (const float*)d_in[8];
  const float* clf_W   = (const float*)d_in[9];
  const float* clf_b   = (const float*)d_in[10];
  float* ws = (float*)d_ws;

  hipMemsetAsync(d_ws, 0, 256, stream);  // barrier counters + argmax slots
  hipLaunchKernelGGL(seq2seq_k, dim3(NB), dim3(BT), 0, stream,
                     x, enc_emb, enc_Wih, enc_Whh, enc_b,
                     dec_emb, dec_Wih, dec_Whh, dec_b, clf_W, clf_b, ws);
  hipLaunchKernelGGL(softmax_k, dim3(TT), dim3(256), 0, stream,
                     ws + OF_LOG, (float*)d_out);
}